// Round 1
// baseline (608.743 us; speedup 1.0000x reference)
//
#include <hip/hip_runtime.h>
#include <cstdint>
#include <cstddef>

#define BZ 4
#define CD 96
#define LL 9216
#define DD 192
#define NS 16
#define RR 6
#define NDBL 38
#define LC 96
#define NG 96

__device__ __forceinline__ float siluf(float x) {
    return x / (1.f + __expf(-x));
}
__device__ __forceinline__ float softplusf(float x) {
    return fmaxf(x, 0.f) + log1pf(__expf(-fabsf(x)));
}

// ---------------------------------------------------------------------------
// Fold LN gain/bias into projection weights:
// gw[d,c] = ln_g[c]*w[d,c];  wsum[d] = sum_c gw[d,c];  bias[d] = b[d] + sum_c ln_b[c]*w[d,c]
__global__ void prep_kernel(const float* kg, const float* kb, const float* kw, const float* kbias,
                            const float* qg, const float* qb, const float* qw, const float* qbias,
                            float* gwK, float* wsumK, float* biasK,
                            float* gwQ, float* wsumQ, float* biasQ) {
    int d = blockIdx.x;
    const float* g  = blockIdx.y ? qg : kg;
    const float* lb = blockIdx.y ? qb : kb;
    const float* w  = blockIdx.y ? qw : kw;
    const float* b2 = blockIdx.y ? qbias : kbias;
    float* gw = blockIdx.y ? gwQ : gwK;
    float* wsv = blockIdx.y ? wsumQ : wsumK;
    float* bv = blockIdx.y ? biasQ : biasK;
    int c = threadIdx.x;
    __shared__ float s1[96], s2[96];
    float wv = w[d * 96 + c];
    float gv = g[c] * wv;
    gw[d * 96 + c] = gv;
    s1[c] = gv;
    s2[c] = lb[c] * wv;
    __syncthreads();
    if (c < 32) { s1[c] += s1[c + 64]; s2[c] += s2[c + 64]; }
    __syncthreads();
    for (int s = 32; s >= 1; s >>= 1) {
        if (c < s) { s1[c] += s1[c + s]; s2[c] += s2[c + s]; }
        __syncthreads();
    }
    if (c == 0) { wsv[d] = s1[0]; bv[d] = b2[d] + s2[0]; }
}

// ---------------------------------------------------------------------------
// Per-token LN stats for K and Q (mean, rsqrt(var+eps))
__global__ __launch_bounds__(256) void stats_kernel(const float* __restrict__ K, const float* __restrict__ Q,
        float* mK, float* invK, float* mQ, float* invQ) {
    int idx = blockIdx.x * 256 + threadIdx.x;   // [0, BZ*LL)
    int b = idx / LL, l = idx % LL;
    const float* kp = K + (size_t)b * CD * LL + l;
    const float* qp = Q + (size_t)b * CD * LL + l;
    float sk = 0.f, ssk = 0.f, sq = 0.f, ssq = 0.f;
    for (int c = 0; c < CD; c++) {
        float kv = kp[(size_t)c * LL];
        float qv = qp[(size_t)c * LL];
        sk += kv; ssk += kv * kv;
        sq += qv; ssq += qv * qv;
    }
    float mk = sk / 96.f, mq = sq / 96.f;
    mK[idx] = mk; mQ[idx] = mq;
    invK[idx] = rsqrtf(fmaxf(ssk / 96.f - mk * mk, 0.f) + 1e-5f);
    invQ[idx] = rsqrtf(fmaxf(ssq / 96.f - mq * mq, 0.f) + 1e-5f);
}

// ---------------------------------------------------------------------------
// 96 -> 192 projection from channel-major (B,C,L) input, optional folded-LN + silu.
// out[b,l,d] = act( inv_l*(sum_c A[b,c,l]*W[d,c] - m_l*wsum[d]) + bias[d] )
template<bool LN, bool ACT>
__global__ __launch_bounds__(256) void proj96_kernel(
    const float* __restrict__ A, const float* __restrict__ W,
    const float* __restrict__ wsum, const float* __restrict__ biasv,
    const float* __restrict__ mArr, const float* __restrict__ invArr,
    float* __restrict__ out)
{
    int b = blockIdx.y;
    int l0 = blockIdx.x * 64;
    int tid = threadIdx.x;
    __shared__ float As[96][68];
    __shared__ float Ws[32][196];
    for (int i = tid; i < 96 * 64; i += 256) {
        int c = i >> 6, ll = i & 63;
        As[c][ll] = A[((size_t)b * CD + c) * LL + l0 + ll];
    }
    int dg = tid & 15, tg = tid >> 4;
    float acc[4][12];
    #pragma unroll
    for (int i = 0; i < 4; i++)
        #pragma unroll
        for (int j = 0; j < 12; j++) acc[i][j] = 0.f;
    for (int c0 = 0; c0 < 96; c0 += 32) {
        __syncthreads();
        for (int i = tid; i < 32 * 192; i += 256) {
            int cc = i & 31, dd = i >> 5;
            Ws[cc][dd] = W[dd * 96 + c0 + cc];
        }
        __syncthreads();
        #pragma unroll 4
        for (int cc = 0; cc < 32; cc++) {
            float4 a = *(const float4*)&As[c0 + cc][tg * 4];
            float w[12];
            #pragma unroll
            for (int j = 0; j < 12; j++) w[j] = Ws[cc][dg * 12 + j];
            #pragma unroll
            for (int j = 0; j < 12; j++) {
                acc[0][j] = fmaf(a.x, w[j], acc[0][j]);
                acc[1][j] = fmaf(a.y, w[j], acc[1][j]);
                acc[2][j] = fmaf(a.z, w[j], acc[2][j]);
                acc[3][j] = fmaf(a.w, w[j], acc[3][j]);
            }
        }
    }
    float wsv[12], bvv[12];
    if (LN) {
        #pragma unroll
        for (int j = 0; j < 12; j++) { wsv[j] = wsum[dg * 12 + j]; bvv[j] = biasv[dg * 12 + j]; }
    }
    #pragma unroll
    for (int i = 0; i < 4; i++) {
        int l = l0 + tg * 4 + i;
        float mv = 0.f, iv = 1.f;
        if (LN) { mv = mArr[b * LL + l]; iv = invArr[b * LL + l]; }
        float* op = out + ((size_t)b * LL + l) * DD + dg * 12;
        #pragma unroll
        for (int q = 0; q < 3; q++) {
            float4 o;
            float v[4];
            #pragma unroll
            for (int e = 0; e < 4; e++) {
                int j = q * 4 + e;
                float vv = acc[i][j];
                if (LN) vv = iv * (vv - mv * wsv[j]) + bvv[j];
                if (ACT) vv = siluf(vv);
                v[e] = vv;
            }
            o.x = v[0]; o.y = v[1]; o.z = v[2]; o.w = v[3];
            *(float4*)(op + q * 4) = o;
        }
    }
}

// ---------------------------------------------------------------------------
// Depthwise causal conv (k=4) + bias + silu, token-major in/out (B,L,192)
__global__ __launch_bounds__(256) void conv_kernel(const float* __restrict__ xin,
        const float* __restrict__ cw, const float* __restrict__ cb,
        float* __restrict__ u)
{
    int idx = blockIdx.x * 256 + threadIdx.x;   // [0, BZ*LL*DD)
    int d = idx % DD;
    int t = idx / DD;                            // b*LL + l
    int l = t % LL;
    float s = cb[d];
    #pragma unroll
    for (int j = 0; j < 4; j++) {
        int lj = l - 3 + j;
        if (lj >= 0) s = fmaf(cw[d * 4 + j], xin[((size_t)t - 3 + j) * DD + d], s);
    }
    u[(size_t)t * DD + d] = siluf(s);
}

// ---------------------------------------------------------------------------
// Token-major GEMM: out[b,l,dout] = act(sum_k cat(inA,inB)[b,l,k]*W[dout,k] + bias)
// TOUT: transposed store into (B, NREAL, L) for the final out-projection.
template<int KD, int NOUT, int NREAL, int DPT, bool BIAS, bool ACT, bool TOUT>
__global__ __launch_bounds__(256) void gemm_tok_kernel(
    const float* __restrict__ inA, const float* __restrict__ inB,
    const float* __restrict__ W, const float* __restrict__ bias,
    float* __restrict__ out)
{
    int b = blockIdx.y;
    int l0 = blockIdx.x * 64;
    int tid = threadIdx.x;
    __shared__ float As[96][68];
    __shared__ float Ws[32][NOUT + 4];
    int dg, tg;
    if (TOUT) { tg = tid & 15; dg = tid >> 4; }
    else      { dg = tid & 15; tg = tid >> 4; }
    float acc[4][DPT];
    #pragma unroll
    for (int i = 0; i < 4; i++)
        #pragma unroll
        for (int j = 0; j < DPT; j++) acc[i][j] = 0.f;
    for (int k0 = 0; k0 < KD; k0 += 96) {
        const float* src = (k0 < 192) ? inA : inB;
        int koff = (k0 < 192) ? k0 : (k0 - 192);
        __syncthreads();
        for (int i = tid; i < 96 * 64; i += 256) {
            int ll = i / 96, kk = i % 96;
            As[kk][ll] = src[((size_t)b * LL + l0 + ll) * DD + koff + kk];
        }
        for (int c0 = 0; c0 < 96; c0 += 32) {
            __syncthreads();
            for (int i = tid; i < 32 * NOUT; i += 256) {
                int cc = i & 31, dd = i >> 5;
                float wv = 0.f;
                if (NREAL == NOUT || dd < NREAL) wv = W[(size_t)dd * KD + k0 + c0 + cc];
                Ws[cc][dd] = wv;
            }
            __syncthreads();
            #pragma unroll 4
            for (int cc = 0; cc < 32; cc++) {
                float4 a = *(const float4*)&As[c0 + cc][tg * 4];
                float w[DPT];
                #pragma unroll
                for (int j = 0; j < DPT; j++) w[j] = Ws[cc][dg * DPT + j];
                #pragma unroll
                for (int j = 0; j < DPT; j++) {
                    acc[0][j] = fmaf(a.x, w[j], acc[0][j]);
                    acc[1][j] = fmaf(a.y, w[j], acc[1][j]);
                    acc[2][j] = fmaf(a.z, w[j], acc[2][j]);
                    acc[3][j] = fmaf(a.w, w[j], acc[3][j]);
                }
            }
        }
    }
    if (TOUT) {
        #pragma unroll
        for (int j = 0; j < DPT; j++) {
            int c = dg * DPT + j;
            float4 o;
            o.x = acc[0][j]; o.y = acc[1][j]; o.z = acc[2][j]; o.w = acc[3][j];
            *(float4*)(out + ((size_t)b * NREAL + c) * LL + l0 + tg * 4) = o;
        }
    } else {
        #pragma unroll
        for (int i = 0; i < 4; i++) {
            int l = l0 + tg * 4 + i;
            float* op = out + ((size_t)b * LL + l) * NREAL;
            #pragma unroll
            for (int j = 0; j < DPT; j++) {
                int d = dg * DPT + j;
                if (NREAL == NOUT || d < NREAL) {
                    float v = acc[i][j];
                    if (BIAS) v += bias[d];
                    if (ACT) v = siluf(v);
                    op[d] = v;
                }
            }
        }
    }
}

// ---------------------------------------------------------------------------
// delta[b,l,d] = softplus(sum_r xdbl[b,l,r]*dt_w[d,r] + 2*dt_b[d])
__global__ __launch_bounds__(256) void delta_kernel(const float* __restrict__ xdbl,
        const float* __restrict__ dtw, const float* __restrict__ dtb,
        float* __restrict__ delta)
{
    int idx = blockIdx.x * 256 + threadIdx.x;
    int d = idx % DD, t = idx / DD;
    float s = 2.f * dtb[d];
    #pragma unroll
    for (int r = 0; r < RR; r++)
        s = fmaf(xdbl[(size_t)t * NDBL + r], dtw[d * RR + r], s);
    delta[(size_t)t * DD + d] = softplusf(s);
}

// ---------------------------------------------------------------------------
// Chunked selective scan, phase 1: per-chunk decay product P and local state S.
__global__ __launch_bounds__(64) void scan_pass1(
    const float* __restrict__ delta, const float* __restrict__ u,
    const float* __restrict__ xdbl, const float* __restrict__ A_log,
    float* __restrict__ P_ws, float* __restrict__ S_ws)
{
    int g = blockIdx.x, dblk = blockIdx.y, b = blockIdx.z;
    int d = dblk * 64 + threadIdx.x;
    int l0 = g * LC;
    __shared__ float Bc[LC][NS];
    for (int i = threadIdx.x; i < LC * NS; i += 64) {
        int tt = i >> 4, n = i & 15;
        Bc[tt][n] = xdbl[((size_t)b * LL + l0 + tt) * NDBL + RR + n];
    }
    float Av[NS];
    #pragma unroll
    for (int n = 0; n < NS; n++) Av[n] = -__expf(A_log[d * NS + n]);
    float h[NS], P[NS];
    #pragma unroll
    for (int n = 0; n < NS; n++) { h[n] = 0.f; P[n] = 1.f; }
    __syncthreads();
    const float* dp = delta + ((size_t)b * LL + l0) * DD + d;
    const float* up = u + ((size_t)b * LL + l0) * DD + d;
    #pragma unroll 4
    for (int t = 0; t < LC; t++) {
        float dlt = dp[(size_t)t * DD];
        float uu = up[(size_t)t * DD];
        float du = dlt * uu;
        #pragma unroll
        for (int n = 0; n < NS; n++) {
            float a = __expf(dlt * Av[n]);
            h[n] = fmaf(a, h[n], du * Bc[t][n]);
            P[n] *= a;
        }
    }
    size_t o = ((size_t)(b * NG + g) * DD + d) * NS;
    #pragma unroll
    for (int q = 0; q < 4; q++) {
        float4 pv, sv;
        pv.x = P[q*4]; pv.y = P[q*4+1]; pv.z = P[q*4+2]; pv.w = P[q*4+3];
        sv.x = h[q*4]; sv.y = h[q*4+1]; sv.z = h[q*4+2]; sv.w = h[q*4+3];
        *(float4*)(P_ws + o + q * 4) = pv;
        *(float4*)(S_ws + o + q * 4) = sv;
    }
}

// Phase 2: sequential combine across chunks (tiny): H[g+1] = P[g]*H[g] + S[g]
__global__ __launch_bounds__(256) void scan_combine(const float* __restrict__ P_ws,
        const float* __restrict__ S_ws, float* __restrict__ H_ws)
{
    int idx = blockIdx.x * 256 + threadIdx.x;   // [0, BZ*DD*NS)
    int b = idx / (DD * NS);
    int r = idx % (DD * NS);
    size_t base = (size_t)b * NG * DD * NS + r;
    float h = 0.f;
    #pragma unroll 4
    for (int g = 0; g < NG; g++) {
        size_t o = base + (size_t)g * DD * NS;
        H_ws[o] = h;
        h = fmaf(P_ws[o], h, S_ws[o]);
    }
}

// Phase 3: replay with true incoming state; fuse y = (yscan + u*D) * silu(z)
__global__ __launch_bounds__(64) void scan_pass2(
    const float* __restrict__ delta, const float* __restrict__ u,
    const float* __restrict__ xdbl, const float* __restrict__ A_log,
    const float* __restrict__ H_ws, const float* __restrict__ zs,
    const float* __restrict__ Dvec, float* __restrict__ y)
{
    int g = blockIdx.x, dblk = blockIdx.y, b = blockIdx.z;
    int d = dblk * 64 + threadIdx.x;
    int l0 = g * LC;
    __shared__ float Bc[LC][NS];
    __shared__ float Cc[LC][NS];
    for (int i = threadIdx.x; i < LC * NS; i += 64) {
        int tt = i >> 4, n = i & 15;
        size_t base = ((size_t)b * LL + l0 + tt) * NDBL;
        Bc[tt][n] = xdbl[base + RR + n];
        Cc[tt][n] = xdbl[base + RR + NS + n];
    }
    float Av[NS];
    #pragma unroll
    for (int n = 0; n < NS; n++) Av[n] = -__expf(A_log[d * NS + n]);
    float h[NS];
    size_t o = ((size_t)(b * NG + g) * DD + d) * NS;
    #pragma unroll
    for (int q = 0; q < 4; q++) {
        float4 hv = *(const float4*)(H_ws + o + q * 4);
        h[q*4] = hv.x; h[q*4+1] = hv.y; h[q*4+2] = hv.z; h[q*4+3] = hv.w;
    }
    float Dv = Dvec[d];
    __syncthreads();
    const float* dp = delta + ((size_t)b * LL + l0) * DD + d;
    const float* up = u + ((size_t)b * LL + l0) * DD + d;
    const float* zp = zs + ((size_t)b * LL + l0) * DD + d;
    float* yp = y + ((size_t)b * LL + l0) * DD + d;
    #pragma unroll 2
    for (int t = 0; t < LC; t++) {
        float dlt = dp[(size_t)t * DD];
        float uu = up[(size_t)t * DD];
        float du = dlt * uu;
        float yv = 0.f;
        #pragma unroll
        for (int n = 0; n < NS; n++) {
            float a = __expf(dlt * Av[n]);
            h[n] = fmaf(a, h[n], du * Bc[t][n]);
            yv = fmaf(h[n], Cc[t][n], yv);
        }
        float zv = zp[(size_t)t * DD];
        yp[(size_t)t * DD] = (yv + uu * Dv) * zv;
    }
}

// ---------------------------------------------------------------------------
extern "C" void kernel_launch(void* const* d_in, const int* in_sizes, int n_in,
                              void* d_out, int out_size, void* d_ws, size_t ws_size,
                              hipStream_t stream)
{
    (void)in_sizes; (void)n_in; (void)out_size; (void)ws_size;
    const float* x        = (const float*)d_in[0];
    const float* K        = (const float*)d_in[1];
    const float* Q        = (const float*)d_in[2];
    const float* in_projw = (const float*)d_in[3];
    const float* conv_w   = (const float*)d_in[4];
    const float* conv_b   = (const float*)d_in[5];
    const float* k_ln_g   = (const float*)d_in[6];
    const float* k_ln_b   = (const float*)d_in[7];
    const float* k_w      = (const float*)d_in[8];
    const float* k_b      = (const float*)d_in[9];
    const float* q_ln_g   = (const float*)d_in[10];
    const float* q_ln_b   = (const float*)d_in[11];
    const float* q_w      = (const float*)d_in[12];
    const float* q_b      = (const float*)d_in[13];
    const float* dtbc_w   = (const float*)d_in[14];
    const float* dt_w     = (const float*)d_in[15];
    const float* dt_b     = (const float*)d_in[16];
    const float* gate_w   = (const float*)d_in[17];
    const float* gate_b   = (const float*)d_in[18];
    const float* A_log    = (const float*)d_in[19];
    const float* Dvec     = (const float*)d_in[20];
    const float* out_w    = (const float*)d_in[21];
    float* out = (float*)d_out;
    float* ws = (float*)d_ws;

    const size_t S0 = (size_t)BZ * LL * DD;
    float* xin  = ws;                 // reused as zs (silu(z)) after conv consumes it
    float* u    = ws + S0;
    float* Kp   = ws + 2 * S0;        // reused as y after x_dbl consumes Kp
    float* Qp   = ws + 3 * S0;        // reused as delta after z-gemm consumes Qp
    float* xdbl = ws + 4 * S0;        // (B,L,38)
    float* p = xdbl + (size_t)BZ * LL * NDBL;
    float* mK   = p; p += BZ * LL;
    float* invK = p; p += BZ * LL;
    float* mQ   = p; p += BZ * LL;
    float* invQ = p; p += BZ * LL;
    float* gwK  = p; p += DD * CD;
    float* gwQ  = p; p += DD * CD;
    float* wsumK = p; p += DD;
    float* biasK = p; p += DD;
    float* wsumQ = p; p += DD;
    float* biasQ = p; p += DD;
    float* P_ws = p; p += (size_t)BZ * NG * DD * NS;
    float* S_ws = p; p += (size_t)BZ * NG * DD * NS;
    float* H_ws = p; p += (size_t)BZ * NG * DD * NS;
    float* zs    = xin;
    float* delta = Qp;
    float* yb    = Kp;

    prep_kernel<<<dim3(DD, 2), 96, 0, stream>>>(k_ln_g, k_ln_b, k_w, k_b,
        q_ln_g, q_ln_b, q_w, q_b, gwK, wsumK, biasK, gwQ, wsumQ, biasQ);
    stats_kernel<<<(BZ * LL) / 256, 256, 0, stream>>>(K, Q, mK, invK, mQ, invQ);
    proj96_kernel<false, false><<<dim3(LL / 64, BZ), 256, 0, stream>>>(
        x, in_projw, nullptr, nullptr, nullptr, nullptr, xin);
    proj96_kernel<true, true><<<dim3(LL / 64, BZ), 256, 0, stream>>>(
        K, gwK, wsumK, biasK, mK, invK, Kp);
    proj96_kernel<true, true><<<dim3(LL / 64, BZ), 256, 0, stream>>>(
        Q, gwQ, wsumQ, biasQ, mQ, invQ, Qp);
    conv_kernel<<<(BZ * LL * DD) / 256, 256, 0, stream>>>(xin, conv_w, conv_b, u);
    gemm_tok_kernel<384, 48, NDBL, 3, false, false, false><<<dim3(LL / 64, BZ), 256, 0, stream>>>(
        u, Kp, dtbc_w, nullptr, xdbl);
    gemm_tok_kernel<384, 192, 192, 12, true, true, false><<<dim3(LL / 64, BZ), 256, 0, stream>>>(
        u, Qp, gate_w, gate_b, zs);
    delta_kernel<<<(BZ * LL * DD) / 256, 256, 0, stream>>>(xdbl, dt_w, dt_b, delta);
    scan_pass1<<<dim3(NG, DD / 64, BZ), 64, 0, stream>>>(delta, u, xdbl, A_log, P_ws, S_ws);
    scan_combine<<<(BZ * DD * NS) / 256, 256, 0, stream>>>(P_ws, S_ws, H_ws);
    scan_pass2<<<dim3(NG, DD / 64, BZ), 64, 0, stream>>>(delta, u, xdbl, A_log, H_ws, zs, Dvec, yb);
    gemm_tok_kernel<192, 96, 96, 6, false, false, true><<<dim3(LL / 64, BZ), 256, 0, stream>>>(
        yb, nullptr, out_w, nullptr, out);
}

// Round 2
// 472.752 us; speedup vs baseline: 1.2877x; 1.2877x over previous
//
#include <hip/hip_runtime.h>
#include <cstdint>
#include <cstddef>

#define BZ 4
#define CD 96
#define LL 9216
#define DD 192
#define NS 16
#define RR 6
#define NDBL 38
#define LC 64
#define NG 144
#define MTOK (BZ * LL)

#define SA 256.0f
#define SW 1024.0f
#define SY 16.0f

typedef _Float16 f16x8 __attribute__((ext_vector_type(8)));
typedef float f32x4 __attribute__((ext_vector_type(4)));

__device__ __forceinline__ float siluf(float x) {
    return x / (1.f + __expf(-x));
}
__device__ __forceinline__ float softplusf(float x) {
    return fmaxf(x, 0.f) + log1pf(__expf(-fabsf(x)));
}

// ---------------------------------------------------------------------------
// Fold LN gain/bias into projection weights (fp32 staging for the splitter):
// gw[d,c] = ln_g[c]*w[d,c];  wsum[d] = sum_c gw[d,c];  bias[d] = b[d] + sum_c ln_b[c]*w[d,c]
__global__ void prep_kernel(const float* kg, const float* kb, const float* kw, const float* kbias,
                            const float* qg, const float* qb, const float* qw, const float* qbias,
                            float* gwK, float* wsumK, float* biasK,
                            float* gwQ, float* wsumQ, float* biasQ) {
    int d = blockIdx.x;
    const float* g  = blockIdx.y ? qg : kg;
    const float* lb = blockIdx.y ? qb : kb;
    const float* w  = blockIdx.y ? qw : kw;
    const float* b2 = blockIdx.y ? qbias : kbias;
    float* gw = blockIdx.y ? gwQ : gwK;
    float* wsv = blockIdx.y ? wsumQ : wsumK;
    float* bv = blockIdx.y ? biasQ : biasK;
    int c = threadIdx.x;
    __shared__ float s1[96], s2[96];
    float wv = w[d * 96 + c];
    float gv = g[c] * wv;
    gw[d * 96 + c] = gv;
    s1[c] = gv;
    s2[c] = lb[c] * wv;
    __syncthreads();
    if (c < 32) { s1[c] += s1[c + 64]; s2[c] += s2[c + 64]; }
    __syncthreads();
    for (int s = 32; s >= 1; s >>= 1) {
        if (c < s) { s1[c] += s1[c + s]; s2[c] += s2[c + s]; }
        __syncthreads();
    }
    if (c == 0) { wsv[d] = s1[0]; bv[d] = b2[d] + s2[0]; }
}

// ---------------------------------------------------------------------------
// Split a weight matrix [N,K] fp32 into hi/lo f16 planes [Npad,K], scaled by SW.
__global__ __launch_bounds__(256) void split_w_kernel(const float* __restrict__ src,
        _Float16* __restrict__ hi, _Float16* __restrict__ lo, int N, int K, int Npad) {
    int idx = blockIdx.x * 256 + threadIdx.x;
    if (idx >= Npad * K) return;
    int d = idx / K;
    float v = (d < N) ? src[idx] * SW : 0.f;
    _Float16 h = (_Float16)v;
    hi[idx] = h;
    lo[idx] = (_Float16)(v - (float)h);
}

// ---------------------------------------------------------------------------
// MFMA projection from channel-major (B,C,L) input, K=96, N=192.
// LN variant: fused per-token LN stats (from staged tile) + folded-LN epilogue
// + silu + split f16 output. !LN: plain fp32 output (xin for conv).
template<bool LN>
__global__ __launch_bounds__(256) void mfma_projCH(
    const float* __restrict__ A,
    const _Float16* __restrict__ Wh, const _Float16* __restrict__ Wl,
    const float* __restrict__ wsum, const float* __restrict__ biasv,
    float* __restrict__ outF,
    _Float16* __restrict__ outH, _Float16* __restrict__ outL)
{
    int b = blockIdx.y;
    int l0 = blockIdx.x * 64;
    int tid = threadIdx.x;
    int lane = tid & 63, w = tid >> 6;
    __shared__ __align__(16) _Float16 Ah[64 * 104];
    __shared__ __align__(16) _Float16 Al[64 * 104];
    __shared__ float sm[64], siv[64];
    __shared__ float red1[256], red2[256];
    // stage + split (transpose: LDS is [token][c])
    for (int i = tid; i < 96 * 64; i += 256) {
        int c = i >> 6, l = i & 63;
        float v = A[((size_t)b * CD + c) * LL + l0 + l] * SA;
        _Float16 h = (_Float16)v;
        Ah[l * 104 + c] = h;
        Al[l * 104 + c] = (_Float16)(v - (float)h);
    }
    __syncthreads();
    if (LN) {
        int tl = tid >> 2, p = tid & 3;
        float s = 0.f, ss = 0.f;
        for (int j = 0; j < 24; j++) {
            int c = p * 24 + j;
            float v = ((float)Ah[tl * 104 + c] + (float)Al[tl * 104 + c]) * (1.f / SA);
            s += v; ss += v * v;
        }
        red1[tid] = s; red2[tid] = ss;
        __syncthreads();
        if (tid < 64) {
            float s4 = red1[tid * 4] + red1[tid * 4 + 1] + red1[tid * 4 + 2] + red1[tid * 4 + 3];
            float q4 = red2[tid * 4] + red2[tid * 4 + 1] + red2[tid * 4 + 2] + red2[tid * 4 + 3];
            float m = s4 / 96.f;
            sm[tid] = m;
            siv[tid] = rsqrtf(fmaxf(q4 / 96.f - m * m, 0.f) + 1e-5f);
        }
        __syncthreads();
    }
    int col = lane & 15, quad = lane >> 4;
    int n0 = w * 48;
    f32x4 zv4 = {0.f, 0.f, 0.f, 0.f};
    f32x4 acc[4][3];
    #pragma unroll
    for (int mi = 0; mi < 4; mi++)
        #pragma unroll
        for (int ni = 0; ni < 3; ni++) acc[mi][ni] = zv4;
    for (int c0 = 0; c0 < 96; c0 += 32) {
        f16x8 afh[4], afl[4], bfh[3], bfl[3];
        #pragma unroll
        for (int mi = 0; mi < 4; mi++) {
            int off = (16 * mi + col) * 104 + c0 + quad * 8;
            afh[mi] = *(const f16x8*)&Ah[off];
            afl[mi] = *(const f16x8*)&Al[off];
        }
        #pragma unroll
        for (int ni = 0; ni < 3; ni++) {
            size_t off = (size_t)(n0 + ni * 16 + col) * 96 + c0 + quad * 8;
            bfh[ni] = *(const f16x8*)&Wh[off];
            bfl[ni] = *(const f16x8*)&Wl[off];
        }
        #pragma unroll
        for (int mi = 0; mi < 4; mi++)
            #pragma unroll
            for (int ni = 0; ni < 3; ni++) {
                acc[mi][ni] = __builtin_amdgcn_mfma_f32_16x16x32_f16(afh[mi], bfl[ni], acc[mi][ni], 0, 0, 0);
                acc[mi][ni] = __builtin_amdgcn_mfma_f32_16x16x32_f16(afl[mi], bfh[ni], acc[mi][ni], 0, 0, 0);
                acc[mi][ni] = __builtin_amdgcn_mfma_f32_16x16x32_f16(afh[mi], bfh[ni], acc[mi][ni], 0, 0, 0);
            }
    }
    const float isc = 1.f / (SA * SW);
    #pragma unroll
    for (int ni = 0; ni < 3; ni++) {
        int d = n0 + ni * 16 + col;
        float wsv = LN ? wsum[d] : 0.f;
        float bvv = LN ? biasv[d] : 0.f;
        #pragma unroll
        for (int mi = 0; mi < 4; mi++)
            #pragma unroll
            for (int r = 0; r < 4; r++) {
                int tl = mi * 16 + quad * 4 + r;
                float v = acc[mi][ni][r] * isc;
                size_t t = (size_t)b * LL + l0 + tl;
                if (LN) {
                    v = (v - sm[tl] * wsv) * siv[tl] + bvv;
                    v = siluf(v) * SA;
                    _Float16 h = (_Float16)v;
                    outH[t * DD + d] = h;
                    outL[t * DD + d] = (_Float16)(v - (float)h);
                } else {
                    outF[t * DD + d] = v;
                }
            }
    }
}

// ---------------------------------------------------------------------------
// Depthwise causal conv (k=4) + bias + silu -> split f16 u planes (x SA)
__global__ __launch_bounds__(256) void conv_kernel(const float* __restrict__ xin,
        const float* __restrict__ cw, const float* __restrict__ cb,
        _Float16* __restrict__ uh, _Float16* __restrict__ ul)
{
    int idx = blockIdx.x * 256 + threadIdx.x;
    int d = idx % DD;
    int t = idx / DD;
    int l = t % LL;
    float s = cb[d];
    #pragma unroll
    for (int j = 0; j < 4; j++) {
        int lj = l - 3 + j;
        if (lj >= 0) s = fmaf(cw[d * 4 + j], xin[((size_t)t - 3 + j) * DD + d], s);
    }
    float u = siluf(s) * SA;
    _Float16 h = (_Float16)u;
    uh[(size_t)t * DD + d] = h;
    ul[(size_t)t * DD + d] = (_Float16)(u - (float)h);
}

// ---------------------------------------------------------------------------
// Token-major MFMA GEMM on f16x2 split planes. A = concat(A0, A1) widths 192 each
// (KD=384) or A0 alone (KD=192). Wave tile 64 tokens x 48 outs. Block = BR x BC waves.
// EPI: 0 = silu fp32 (z-gate), 1 = plain fp32 with d<NREAL predicate (xdbl),
//      2 = transposed fp32 float4 store (final out, (B,C,L)).
template<int BR, int BC, int KD, int NREAL, int EPI>
__global__ __launch_bounds__(256) void mfma_gemm_tok(
    const _Float16* __restrict__ A0h, const _Float16* __restrict__ A0l,
    const _Float16* __restrict__ A1h, const _Float16* __restrict__ A1l,
    const _Float16* __restrict__ Wh, const _Float16* __restrict__ Wl,
    const float* __restrict__ bias, float oscale, float* __restrict__ outF)
{
    int tid = threadIdx.x;
    int lane = tid & 63, w = tid >> 6;
    int mr = w % BR, nc = w / BR;
    int t0 = blockIdx.x * (BR * 64) + mr * 64;
    int n0 = nc * 48;
    int col = lane & 15, quad = lane >> 4;
    f32x4 zv4 = {0.f, 0.f, 0.f, 0.f};
    f32x4 acc[4][3];
    #pragma unroll
    for (int mi = 0; mi < 4; mi++)
        #pragma unroll
        for (int ni = 0; ni < 3; ni++) acc[mi][ni] = zv4;
    for (int k0 = 0; k0 < KD; k0 += 32) {
        const _Float16* Ah = (KD == 384 && k0 >= 192) ? A1h : A0h;
        const _Float16* Al = (KD == 384 && k0 >= 192) ? A1l : A0l;
        int kc = (KD == 384 && k0 >= 192) ? k0 - 192 : k0;
        f16x8 afh[4], afl[4], bfh[3], bfl[3];
        #pragma unroll
        for (int mi = 0; mi < 4; mi++) {
            size_t off = (size_t)(t0 + mi * 16 + col) * DD + kc + quad * 8;
            afh[mi] = *(const f16x8*)&Ah[off];
            afl[mi] = *(const f16x8*)&Al[off];
        }
        #pragma unroll
        for (int ni = 0; ni < 3; ni++) {
            size_t off = (size_t)(n0 + ni * 16 + col) * KD + k0 + quad * 8;
            bfh[ni] = *(const f16x8*)&Wh[off];
            bfl[ni] = *(const f16x8*)&Wl[off];
        }
        #pragma unroll
        for (int mi = 0; mi < 4; mi++)
            #pragma unroll
            for (int ni = 0; ni < 3; ni++) {
                acc[mi][ni] = __builtin_amdgcn_mfma_f32_16x16x32_f16(afh[mi], bfl[ni], acc[mi][ni], 0, 0, 0);
                acc[mi][ni] = __builtin_amdgcn_mfma_f32_16x16x32_f16(afl[mi], bfh[ni], acc[mi][ni], 0, 0, 0);
                acc[mi][ni] = __builtin_amdgcn_mfma_f32_16x16x32_f16(afh[mi], bfh[ni], acc[mi][ni], 0, 0, 0);
            }
    }
    if (EPI == 2) {
        int bq = t0 / LL;
        int lb = t0 % LL;
        #pragma unroll
        for (int ni = 0; ni < 3; ni++) {
            int d = n0 + ni * 16 + col;
            #pragma unroll
            for (int mi = 0; mi < 4; mi++) {
                f32x4 v;
                #pragma unroll
                for (int r = 0; r < 4; r++) v[r] = acc[mi][ni][r] * oscale;
                *(f32x4*)&outF[((size_t)(bq * 96 + d)) * LL + lb + mi * 16 + quad * 4] = v;
            }
        }
    } else {
        #pragma unroll
        for (int ni = 0; ni < 3; ni++) {
            int d = n0 + ni * 16 + col;
            float bv = (EPI == 0) ? bias[d] : 0.f;
            #pragma unroll
            for (int mi = 0; mi < 4; mi++)
                #pragma unroll
                for (int r = 0; r < 4; r++) {
                    size_t t = t0 + mi * 16 + quad * 4 + r;
                    float v = acc[mi][ni][r] * oscale;
                    if (EPI == 0) {
                        outF[t * DD + d] = siluf(v + bv);
                    } else {
                        if (d < NREAL) outF[t * (size_t)NREAL + d] = v;
                    }
                }
        }
    }
}

// ---------------------------------------------------------------------------
// Chunked selective scan, delta fused (softplus(dt @ dt_w.T + 2 dt_b)),
// u reconstructed from split planes.
__global__ __launch_bounds__(64) void scan_pass1(
    const _Float16* __restrict__ uh, const _Float16* __restrict__ ul,
    const float* __restrict__ xdbl, const float* __restrict__ A_log,
    const float* __restrict__ dtw, const float* __restrict__ dtb,
    float* __restrict__ P_ws, float* __restrict__ S_ws)
{
    int g = blockIdx.x, dblk = blockIdx.y, b = blockIdx.z;
    int d = dblk * 64 + threadIdx.x;
    int l0 = g * LC;
    __shared__ float Bc[LC][NS];
    __shared__ float dts[LC][8];
    for (int i = threadIdx.x; i < LC * NS; i += 64) {
        int tt = i >> 4, n = i & 15;
        Bc[tt][n] = xdbl[((size_t)b * LL + l0 + tt) * NDBL + RR + n];
    }
    for (int i = threadIdx.x; i < LC * RR; i += 64) {
        int tt = i / RR, r = i % RR;
        dts[tt][r] = xdbl[((size_t)b * LL + l0 + tt) * NDBL + r];
    }
    float Av[NS];
    #pragma unroll
    for (int n = 0; n < NS; n++) Av[n] = -__expf(A_log[d * NS + n]);
    float w6[RR];
    #pragma unroll
    for (int r = 0; r < RR; r++) w6[r] = dtw[d * RR + r];
    float b2 = 2.f * dtb[d];
    float h[NS], P[NS];
    #pragma unroll
    for (int n = 0; n < NS; n++) { h[n] = 0.f; P[n] = 1.f; }
    __syncthreads();
    const _Float16* uhp = uh + ((size_t)b * LL + l0) * DD + d;
    const _Float16* ulp = ul + ((size_t)b * LL + l0) * DD + d;
    #pragma unroll 2
    for (int t = 0; t < LC; t++) {
        float s = b2;
        #pragma unroll
        for (int r = 0; r < RR; r++) s = fmaf(dts[t][r], w6[r], s);
        float dlt = softplusf(s);
        float uu = ((float)uhp[(size_t)t * DD] + (float)ulp[(size_t)t * DD]) * (1.f / SA);
        float du = dlt * uu;
        #pragma unroll
        for (int n = 0; n < NS; n++) {
            float a = __expf(dlt * Av[n]);
            h[n] = fmaf(a, h[n], du * Bc[t][n]);
            P[n] *= a;
        }
    }
    size_t o = ((size_t)(b * NG + g) * DD + d) * NS;
    #pragma unroll
    for (int q = 0; q < 4; q++) {
        f32x4 pv, sv;
        #pragma unroll
        for (int e = 0; e < 4; e++) { pv[e] = P[q * 4 + e]; sv[e] = h[q * 4 + e]; }
        *(f32x4*)(P_ws + o + q * 4) = pv;
        *(f32x4*)(S_ws + o + q * 4) = sv;
    }
}

__global__ __launch_bounds__(256) void scan_combine(const float* __restrict__ P_ws,
        const float* __restrict__ S_ws, float* __restrict__ H_ws)
{
    int idx = blockIdx.x * 256 + threadIdx.x;
    int b = idx / (DD * NS);
    int r = idx % (DD * NS);
    size_t base = (size_t)b * NG * DD * NS + r;
    float h = 0.f;
    #pragma unroll 8
    for (int g = 0; g < NG; g++) {
        size_t o = base + (size_t)g * DD * NS;
        H_ws[o] = h;
        h = fmaf(P_ws[o], h, S_ws[o]);
    }
}

__global__ __launch_bounds__(64) void scan_pass2(
    const _Float16* __restrict__ uh, const _Float16* __restrict__ ul,
    const float* __restrict__ xdbl, const float* __restrict__ A_log,
    const float* __restrict__ dtw, const float* __restrict__ dtb,
    const float* __restrict__ H_ws, const float* __restrict__ zs,
    const float* __restrict__ Dvec,
    _Float16* __restrict__ yh, _Float16* __restrict__ yl)
{
    int g = blockIdx.x, dblk = blockIdx.y, b = blockIdx.z;
    int d = dblk * 64 + threadIdx.x;
    int l0 = g * LC;
    __shared__ float Bc[LC][NS];
    __shared__ float Cc[LC][NS];
    __shared__ float dts[LC][8];
    for (int i = threadIdx.x; i < LC * NS; i += 64) {
        int tt = i >> 4, n = i & 15;
        size_t base = ((size_t)b * LL + l0 + tt) * NDBL;
        Bc[tt][n] = xdbl[base + RR + n];
        Cc[tt][n] = xdbl[base + RR + NS + n];
    }
    for (int i = threadIdx.x; i < LC * RR; i += 64) {
        int tt = i / RR, r = i % RR;
        dts[tt][r] = xdbl[((size_t)b * LL + l0 + tt) * NDBL + r];
    }
    float Av[NS];
    #pragma unroll
    for (int n = 0; n < NS; n++) Av[n] = -__expf(A_log[d * NS + n]);
    float w6[RR];
    #pragma unroll
    for (int r = 0; r < RR; r++) w6[r] = dtw[d * RR + r];
    float b2 = 2.f * dtb[d];
    float h[NS];
    size_t o = ((size_t)(b * NG + g) * DD + d) * NS;
    #pragma unroll
    for (int q = 0; q < 4; q++) {
        f32x4 hv = *(const f32x4*)(H_ws + o + q * 4);
        #pragma unroll
        for (int e = 0; e < 4; e++) h[q * 4 + e] = hv[e];
    }
    float Dv = Dvec[d];
    __syncthreads();
    const _Float16* uhp = uh + ((size_t)b * LL + l0) * DD + d;
    const _Float16* ulp = ul + ((size_t)b * LL + l0) * DD + d;
    const float* zp = zs + ((size_t)b * LL + l0) * DD + d;
    _Float16* yhp = yh + ((size_t)b * LL + l0) * DD + d;
    _Float16* ylp = yl + ((size_t)b * LL + l0) * DD + d;
    #pragma unroll 2
    for (int t = 0; t < LC; t++) {
        float s = b2;
        #pragma unroll
        for (int r = 0; r < RR; r++) s = fmaf(dts[t][r], w6[r], s);
        float dlt = softplusf(s);
        float uu = ((float)uhp[(size_t)t * DD] + (float)ulp[(size_t)t * DD]) * (1.f / SA);
        float du = dlt * uu;
        float yv = 0.f;
        #pragma unroll
        for (int n = 0; n < NS; n++) {
            float a = __expf(dlt * Av[n]);
            h[n] = fmaf(a, h[n], du * Bc[t][n]);
            yv = fmaf(h[n], Cc[t][n], yv);
        }
        float zv = zp[(size_t)t * DD];
        float y = (yv + uu * Dv) * zv * SY;
        _Float16 hh = (_Float16)y;
        yhp[(size_t)t * DD] = hh;
        ylp[(size_t)t * DD] = (_Float16)(y - (float)hh);
    }
}

// ---------------------------------------------------------------------------
extern "C" void kernel_launch(void* const* d_in, const int* in_sizes, int n_in,
                              void* d_out, int out_size, void* d_ws, size_t ws_size,
                              hipStream_t stream)
{
    (void)in_sizes; (void)n_in; (void)out_size; (void)ws_size;
    const float* x        = (const float*)d_in[0];
    const float* K        = (const float*)d_in[1];
    const float* Q        = (const float*)d_in[2];
    const float* in_projw = (const float*)d_in[3];
    const float* conv_w   = (const float*)d_in[4];
    const float* conv_b   = (const float*)d_in[5];
    const float* k_ln_g   = (const float*)d_in[6];
    const float* k_ln_b   = (const float*)d_in[7];
    const float* k_w      = (const float*)d_in[8];
    const float* k_b      = (const float*)d_in[9];
    const float* q_ln_g   = (const float*)d_in[10];
    const float* q_ln_b   = (const float*)d_in[11];
    const float* q_w      = (const float*)d_in[12];
    const float* q_b      = (const float*)d_in[13];
    const float* dtbc_w   = (const float*)d_in[14];
    const float* dt_w     = (const float*)d_in[15];
    const float* dt_b     = (const float*)d_in[16];
    const float* A_log    = (const float*)d_in[19];
    const float* Dvec     = (const float*)d_in[20];
    const float* out_w    = (const float*)d_in[21];
    const float* gate_w   = (const float*)d_in[17];
    const float* gate_b   = (const float*)d_in[18];
    float* out = (float*)d_out;

    const size_t S0 = (size_t)MTOK * DD;
    char* base = (char*)d_ws;
    size_t off = 0;
    auto alloc = [&](size_t bytes) {
        char* p = base + off;
        off += (bytes + 255) & ~(size_t)255;
        return p;
    };
    float*     xin   = (float*)alloc(S0 * 4);            // reused as zs
    _Float16*  uH    = (_Float16*)alloc(S0 * 2);
    _Float16*  uL    = (_Float16*)alloc(S0 * 2);
    _Float16*  KpH   = (_Float16*)alloc(S0 * 2);         // reused as yH
    _Float16*  KpL   = (_Float16*)alloc(S0 * 2);         // reused as yL
    _Float16*  QpH   = (_Float16*)alloc(S0 * 2);
    _Float16*  QpL   = (_Float16*)alloc(S0 * 2);
    float*     xdbl  = (float*)alloc((size_t)MTOK * NDBL * 4);
    float*     gwK   = (float*)alloc(DD * CD * 4);
    float*     gwQ   = (float*)alloc(DD * CD * 4);
    float*     wsumK = (float*)alloc(DD * 4);
    float*     biasK = (float*)alloc(DD * 4);
    float*     wsumQ = (float*)alloc(DD * 4);
    float*     biasQ = (float*)alloc(DD * 4);
    _Float16*  ipWh  = (_Float16*)alloc(DD * CD * 2);
    _Float16*  ipWl  = (_Float16*)alloc(DD * CD * 2);
    _Float16*  kWh   = (_Float16*)alloc(DD * CD * 2);
    _Float16*  kWl   = (_Float16*)alloc(DD * CD * 2);
    _Float16*  qWh   = (_Float16*)alloc(DD * CD * 2);
    _Float16*  qWl   = (_Float16*)alloc(DD * CD * 2);
    _Float16*  dbWh  = (_Float16*)alloc(48 * 384 * 2);
    _Float16*  dbWl  = (_Float16*)alloc(48 * 384 * 2);
    _Float16*  gWh   = (_Float16*)alloc(DD * 384 * 2);
    _Float16*  gWl   = (_Float16*)alloc(DD * 384 * 2);
    _Float16*  oWh   = (_Float16*)alloc(96 * DD * 2);
    _Float16*  oWl   = (_Float16*)alloc(96 * DD * 2);
    float*     P_ws  = (float*)alloc((size_t)BZ * NG * DD * NS * 4);
    float*     S_ws  = (float*)alloc((size_t)BZ * NG * DD * NS * 4);
    float*     H_ws  = (float*)alloc((size_t)BZ * NG * DD * NS * 4);
    float*    zs = xin;
    _Float16* yH = KpH;
    _Float16* yL = KpL;

    prep_kernel<<<dim3(DD, 2), 96, 0, stream>>>(k_ln_g, k_ln_b, k_w, k_b,
        q_ln_g, q_ln_b, q_w, q_b, gwK, wsumK, biasK, gwQ, wsumQ, biasQ);
    split_w_kernel<<<(DD * CD + 255) / 256, 256, 0, stream>>>(in_projw, ipWh, ipWl, DD, CD, DD);
    split_w_kernel<<<(DD * CD + 255) / 256, 256, 0, stream>>>(gwK, kWh, kWl, DD, CD, DD);
    split_w_kernel<<<(DD * CD + 255) / 256, 256, 0, stream>>>(gwQ, qWh, qWl, DD, CD, DD);
    split_w_kernel<<<(48 * 384 + 255) / 256, 256, 0, stream>>>(dtbc_w, dbWh, dbWl, NDBL, 384, 48);
    split_w_kernel<<<(DD * 384 + 255) / 256, 256, 0, stream>>>(gate_w, gWh, gWl, DD, 384, DD);
    split_w_kernel<<<(96 * DD + 255) / 256, 256, 0, stream>>>(out_w, oWh, oWl, 96, DD, 96);

    mfma_projCH<false><<<dim3(LL / 64, BZ), 256, 0, stream>>>(
        x, ipWh, ipWl, nullptr, nullptr, xin, nullptr, nullptr);
    mfma_projCH<true><<<dim3(LL / 64, BZ), 256, 0, stream>>>(
        K, kWh, kWl, wsumK, biasK, nullptr, KpH, KpL);
    mfma_projCH<true><<<dim3(LL / 64, BZ), 256, 0, stream>>>(
        Q, qWh, qWl, wsumQ, biasQ, nullptr, QpH, QpL);
    conv_kernel<<<(MTOK * DD) / 256, 256, 0, stream>>>(xin, conv_w, conv_b, uH, uL);
    mfma_gemm_tok<4, 1, 384, NDBL, 1><<<MTOK / 256, 256, 0, stream>>>(
        uH, uL, KpH, KpL, dbWh, dbWl, nullptr, 1.f / (SA * SW), xdbl);
    mfma_gemm_tok<1, 4, 384, 192, 0><<<MTOK / 64, 256, 0, stream>>>(
        uH, uL, QpH, QpL, gWh, gWl, gate_b, 1.f / (SA * SW), zs);
    scan_pass1<<<dim3(NG, DD / 64, BZ), 64, 0, stream>>>(
        uH, uL, xdbl, A_log, dt_w, dt_b, P_ws, S_ws);
    scan_combine<<<(BZ * DD * NS) / 256, 256, 0, stream>>>(P_ws, S_ws, H_ws);
    scan_pass2<<<dim3(NG, DD / 64, BZ), 64, 0, stream>>>(
        uH, uL, xdbl, A_log, dt_w, dt_b, H_ws, zs, Dvec, yH, yL);
    mfma_gemm_tok<2, 2, 192, 96, 2><<<MTOK / 128, 256, 0, stream>>>(
        yH, yL, nullptr, nullptr, oWh, oWl, nullptr, 1.f / (SY * SW), out);
}